// Round 4
// baseline (48858.078 us; speedup 1.0000x reference)
//
#include <hip/hip_runtime.h>

// ---------------- problem constants ----------------
#define PL 400
#define QL 60
#define BB 128
#define EE 512
#define HH 256
#define DD 1024
#define G3 768
#define NBLK 256
#define NTHR 512
#define LDK 72   // padded K stride (shorts) for LDS tiles

typedef __attribute__((ext_vector_type(8))) short bfrag;
typedef __attribute__((ext_vector_type(4))) float facc;

// ---------------- bf16 / math helpers ----------------
__device__ __forceinline__ unsigned short f2bf(float x) {
  unsigned u = __float_as_uint(x);
  return (unsigned short)((u + 0x7fffu + ((u >> 16) & 1u)) >> 16);
}
__device__ __forceinline__ float bf2f(unsigned short h) {
  return __uint_as_float(((unsigned)h) << 16);
}
__device__ __forceinline__ void split_bf(float x, unsigned short& hi, unsigned short& lo) {
  hi = f2bf(x);
  lo = f2bf(x - bf2f(hi));
}
__device__ __forceinline__ unsigned packf(float x) {
  unsigned short hi, lo;
  split_bf(x, hi, lo);
  return ((unsigned)hi << 16) | lo;
}
__device__ __forceinline__ float sigm(float x) {
  return __builtin_amdgcn_rcpf(1.f + __expf(-x));
}
__device__ __forceinline__ float ftanh(float x) {
  float xc = fminf(fmaxf(x, -10.f), 10.f);
  float t = __expf(2.f * xc);
  return (t - 1.f) * __builtin_amdgcn_rcpf(t + 1.f);
}
__device__ __forceinline__ float uf(unsigned long long v) { return __uint_as_float((unsigned)v); }
__device__ __forceinline__ float ufh(unsigned long long v) { return __uint_as_float((unsigned)(v >> 32)); }

// ---------------- agent-scope relaxed atomics (MALL-coherent, no fences) ----------------
__device__ __forceinline__ float ald(const float* p) {
  return __hip_atomic_load((float*)p, __ATOMIC_RELAXED, __HIP_MEMORY_SCOPE_AGENT);
}
__device__ __forceinline__ void ast(float* p, float v) {
  __hip_atomic_store(p, v, __ATOMIC_RELAXED, __HIP_MEMORY_SCOPE_AGENT);
}
__device__ __forceinline__ unsigned aldu(const unsigned* p) {
  return __hip_atomic_load((unsigned*)p, __ATOMIC_RELAXED, __HIP_MEMORY_SCOPE_AGENT);
}
__device__ __forceinline__ void astu(unsigned* p, unsigned v) {
  __hip_atomic_store(p, v, __ATOMIC_RELAXED, __HIP_MEMORY_SCOPE_AGENT);
}
__device__ __forceinline__ unsigned long long aldull(const unsigned long long* p) {
  return __hip_atomic_load((unsigned long long*)p, __ATOMIC_RELAXED, __HIP_MEMORY_SCOPE_AGENT);
}

// ---------------- ws layout ----------------
// fp32 region
constexpr size_t SZ_QT  = (size_t)2 * QL * BB * HH;
constexpr size_t SZ_PT  = (size_t)2 * PL * BB * HH;
constexpr size_t SZ_GP  = (size_t)2 * BB * DD * 4;   // gate partials, interleaved ks 0..3
constexpr size_t SZ_GIP = (size_t)2 * BB * G3 * 4;   // gi partials, interleaved ks 0..3
constexpr size_t SZ_GHP = (size_t)2 * BB * G3;       // gh (k-complete)
constexpr size_t SZ_WST = (size_t)2 * HH * HH;       // Ws transposed fp32
constexpr size_t OFF_QT  = 0;
constexpr size_t OFF_PT  = OFF_QT + SZ_QT;
constexpr size_t OFF_GP  = OFF_PT + SZ_PT;
constexpr size_t OFF_GIP = OFF_GP + SZ_GP;
constexpr size_t OFF_GHP = OFF_GIP + SZ_GIP;
constexpr size_t OFF_WST = OFF_GHP + SZ_GHP;
constexpr size_t F32_TOT = OFF_WST + SZ_WST;
// uint region (packed hi/lo bf16)
constexpr size_t UOFF_UPACK = 0;                         // [d][b][1024] u = [pin|att]
constexpr size_t UOFF_HPACK = UOFF_UPACK + (size_t)2 * BB * DD;  // [d][b][256]
constexpr size_t U_TOT      = UOFF_HPACK + (size_t)2 * BB * HH;
// bf16 (ushort) weight region
constexpr size_t HSZ_WQT = (size_t)2 * HH * EE;
constexpr size_t HSZ_GW  = (size_t)2 * DD * DD;
constexpr size_t HSZ_WIH = (size_t)2 * G3 * DD;
constexpr size_t HSZ_WHH = (size_t)2 * G3 * HH;
constexpr size_t HOFF_WQTH = 0;
constexpr size_t HOFF_WQTL = HOFF_WQTH + HSZ_WQT;
constexpr size_t HOFF_WPTH = HOFF_WQTL + HSZ_WQT;
constexpr size_t HOFF_WPTL = HOFF_WPTH + HSZ_WQT;
constexpr size_t HOFF_GWH  = HOFF_WPTL + HSZ_WQT;
constexpr size_t HOFF_GWL  = HOFF_GWH + HSZ_GW;
constexpr size_t HOFF_WIHH = HOFF_GWL + HSZ_GW;
constexpr size_t HOFF_WIHL = HOFF_WIHH + HSZ_WIH;
constexpr size_t HOFF_WHHH = HOFF_WIHL + HSZ_WIH;
constexpr size_t HOFF_WHHL = HOFF_WHHH + HSZ_WHH;
constexpr size_t H_TOT     = HOFF_WHHL + HSZ_WHH;

// ---------------- grid barrier: flat all-poll, fence-free ----------------
__device__ __forceinline__ void gbar(unsigned* slots, unsigned gen) {
  asm volatile("" ::: "memory");
  __syncthreads();  // drains vmcnt for all waves of this block (release point)
  if (threadIdx.x == 0)
    __hip_atomic_store(&slots[blockIdx.x], gen, __ATOMIC_RELAXED, __HIP_MEMORY_SCOPE_AGENT);
  if (threadIdx.x < NBLK) {
    unsigned sp = 0;
    while (__hip_atomic_load(&slots[threadIdx.x], __ATOMIC_RELAXED, __HIP_MEMORY_SCOPE_AGENT) < gen) {
      __builtin_amdgcn_s_sleep(1);
      if (++sp > (1u << 26)) break;  // hang bailout
    }
  }
  __syncthreads();
  asm volatile("" ::: "memory");
}

// ---------------- unified MFMA GEMM tile ----------------
// M=128 (batch). NT = 128 or 64. K = NCH*64 starting at kbase.
// AMODE 0: A = fp32 plain (asrc/astride)                 [prologue]
// AMODE 1: A = packed uint (apack/apstride)              [gate: upack]
// AMODE 2: A = x = u * sigm(sum4 gp + gateb)             [gi]
// AMODE 3: A = packed uint                               [gh: hpack] (same as 1)
// BSPLIT: B hi/lo (3 MFMA) vs single (2 MFMA). A always hi/lo.
// BGLOBAL: stage B from global per chunk (prologue) vs LDS-resident.
// OATOMIC: C written via agent-atomic stores. cstride: col element stride.
template <int NT, int AMODE, bool BSPLIT, bool BGLOBAL, bool OATOMIC, int NCH>
__device__ void gemm_t(unsigned short* sAh, unsigned short* sAl, unsigned short* warea,
                       const float* asrc, int astride,
                       const unsigned* apack, int apstride,
                       const float* gp4, const float* gateb_d,
                       const unsigned short* bh_g, const unsigned short* bl_g, int bstride,
                       float* dst, int dstride, int cstride, int kbase) {
  const int tid = threadIdx.x;
  const int lane = tid & 63;
  const int w = tid >> 6;
  constexpr int FM = (NT == 128) ? 4 : 2;
  constexpr int FN = 2;
  const int wm = (NT == 128) ? ((w >> 2) << 6) : ((w >> 1) << 5);
  const int wn = (NT == 128) ? ((w & 3) << 5) : ((w & 1) << 5);
  const int lr = lane & 15;
  const int lk = (lane >> 4) << 3;
  constexpr int NLD = 8192 / NTHR;  // 16

  unsigned short* wh = warea;
  unsigned short* wl = BGLOBAL ? (warea + 128 * LDK) : (warea + 4 * NT * LDK);

  const facc fz = {0.f, 0.f, 0.f, 0.f};
  facc acc[FM][FN];
#pragma unroll
  for (int i = 0; i < FM; i++)
#pragma unroll
    for (int j = 0; j < FN; j++) acc[i][j] = fz;

  constexpr bool PF = (AMODE == 1 || AMODE == 3);
  unsigned pva[PF ? NLD : 1], pvb[PF ? NLD : 1];
  if constexpr (PF) {
#pragma unroll
    for (int ii = 0; ii < NLD; ii++) {
      int r = ii * 8 + w;
      pva[ii] = aldu(&apack[(size_t)r * apstride + kbase + lane]);
    }
  }

#pragma unroll
  for (int ch = 0; ch < NCH; ++ch) {
    const int kk0 = kbase + (ch << 6);
    if constexpr (PF) {
      unsigned* cur = (ch & 1) ? pvb : pva;
      unsigned* nxt = (ch & 1) ? pva : pvb;
      if (ch + 1 < NCH) {
#pragma unroll
        for (int ii = 0; ii < NLD; ii++) {
          int r = ii * 8 + w;
          nxt[ii] = aldu(&apack[(size_t)r * apstride + kk0 + 64 + lane]);
        }
      }
#pragma unroll
      for (int ii = 0; ii < NLD; ii++) {
        int r = ii * 8 + w;
        unsigned p = cur[ii];
        sAh[r * LDK + lane] = (unsigned short)(p >> 16);
        sAl[r * LDK + lane] = (unsigned short)(p & 0xffffu);
      }
    } else if constexpr (AMODE == 0) {
#pragma unroll
      for (int ii = 0; ii < NLD; ii++) {
        int r = ii * 8 + w;
        unsigned short uh, ul;
        split_bf(asrc[(size_t)r * astride + kk0 + lane], uh, ul);
        sAh[r * LDK + lane] = uh;
        sAl[r * LDK + lane] = ul;
      }
    } else {  // AMODE 2: x = u * sigm(g)
#pragma unroll
      for (int ii = 0; ii < NLD; ii++) {
        int r = ii * 8 + w;
        int kk = kk0 + lane;
        const unsigned long long* gpe =
            (const unsigned long long*)(gp4 + ((size_t)r * DD + kk) * 4);
        unsigned long long g01 = aldull(gpe);
        unsigned long long g23 = aldull(gpe + 1);
        unsigned p = aldu(&apack[(size_t)r * apstride + kk]);
        float g = gateb_d[kk] + ((uf(g01) + ufh(g01)) + (uf(g23) + ufh(g23)));
        float uv = bf2f((unsigned short)(p >> 16)) + bf2f((unsigned short)(p & 0xffffu));
        unsigned short uh, ul;
        split_bf(uv * sigm(g), uh, ul);
        sAh[r * LDK + lane] = uh;
        sAl[r * LDK + lane] = ul;
      }
    }
    if constexpr (BGLOBAL) {
#pragma unroll
      for (int ii = 0; ii < NLD; ii++) {
        int r = ii * 8 + w;
        wh[r * LDK + lane] = bh_g[(size_t)r * bstride + kk0 + lane];
        wl[r * LDK + lane] = bl_g[(size_t)r * bstride + kk0 + lane];
      }
    }
    // stage barrier: wait LDS writes only; prefetch global loads stay in flight
    asm volatile("s_waitcnt lgkmcnt(0)" ::: "memory");
    __builtin_amdgcn_s_barrier();
    __builtin_amdgcn_sched_barrier(0);

    const int wch = BGLOBAL ? 0 : ch;
#pragma unroll
    for (int k32 = 0; k32 < 64; k32 += 32) {
      bfrag ah[FM], al_[FM], bhf[FN], blf[FN];
#pragma unroll
      for (int f = 0; f < FM; f++) {
        const int ao = (wm + (f << 4) + lr) * LDK + k32 + lk;
        ah[f]  = *(const bfrag*)&sAh[ao];
        al_[f] = *(const bfrag*)&sAl[ao];
      }
#pragma unroll
      for (int f = 0; f < FN; f++) {
        const int bo = (wch * NT + wn + (f << 4) + lr) * LDK + k32 + lk;
        bhf[f] = *(const bfrag*)&wh[bo];
        if constexpr (BSPLIT) blf[f] = *(const bfrag*)&wl[bo];
      }
#pragma unroll
      for (int i = 0; i < FM; i++)
#pragma unroll
        for (int j = 0; j < FN; j++) {
          acc[i][j] = __builtin_amdgcn_mfma_f32_16x16x32_bf16(al_[i], bhf[j], acc[i][j], 0, 0, 0);
          if constexpr (BSPLIT)
            acc[i][j] = __builtin_amdgcn_mfma_f32_16x16x32_bf16(ah[i], blf[j], acc[i][j], 0, 0, 0);
          acc[i][j] = __builtin_amdgcn_mfma_f32_16x16x32_bf16(ah[i], bhf[j], acc[i][j], 0, 0, 0);
        }
    }
    __builtin_amdgcn_sched_barrier(0);
    __builtin_amdgcn_s_barrier();
    __builtin_amdgcn_sched_barrier(0);
  }
  const int orow = (lane >> 4) << 2;
  const int ocol = lane & 15;
#pragma unroll
  for (int i = 0; i < FM; i++)
#pragma unroll
    for (int j = 0; j < FN; j++)
#pragma unroll
      for (int q = 0; q < 4; q++) {
        float* p = &dst[(size_t)(wm + (i << 4) + orow + q) * dstride +
                        (size_t)(wn + (j << 4) + ocol) * cstride];
        if constexpr (OATOMIC) ast(p, acc[i][j][q]);
        else *p = acc[i][j][q];
      }
}

// ---------------- setup kernels ----------------
__global__ void __launch_bounds__(256) k_transpose_qp(
    const float* __restrict__ Wq, const float* __restrict__ Wp,
    unsigned short* __restrict__ wqth, unsigned short* __restrict__ wqtl,
    unsigned short* __restrict__ wpth, unsigned short* __restrict__ wptl) {
  __shared__ float tile[64 * 65];
  const int blk = blockIdx.x;
  const int mat = blk >> 6;
  const int rem = blk & 63;
  const int d = rem >> 5;
  const int rem2 = rem & 31;
  const int kt = rem2 >> 2;
  const int nt = rem2 & 3;
  const float* src = mat ? Wp : Wq;
  unsigned short* dh = mat ? wpth : wqth;
  unsigned short* dl = mat ? wptl : wqtl;
  const int tid = threadIdx.x;
  for (int i = tid; i < 4096; i += 256) {
    int kr = i >> 6, nc = i & 63;
    tile[kr * 65 + nc] = src[((size_t)d * EE + kt * 64 + kr) * HH + nt * 64 + nc];
  }
  __syncthreads();
  for (int i = tid; i < 4096; i += 256) {
    int n = i >> 6, k = i & 63;
    unsigned short hi, lo;
    split_bf(tile[k * 65 + n], hi, lo);
    size_t o = ((size_t)d * HH + nt * 64 + n) * EE + kt * 64 + k;
    dh[o] = hi; dl[o] = lo;
  }
}

__global__ void __launch_bounds__(256) k_split_w(
    const float* __restrict__ gw, const float* __restrict__ wih, const float* __restrict__ whh,
    unsigned short* __restrict__ gwh, unsigned short* __restrict__ gwl,
    unsigned short* __restrict__ wihh, unsigned short* __restrict__ wihl,
    unsigned short* __restrict__ whhh, unsigned short* __restrict__ whhl) {
  const size_t N1 = HSZ_GW, N2 = HSZ_WIH, N3 = HSZ_WHH;
  for (size_t i = (size_t)blockIdx.x * 256 + threadIdx.x; i < N1 + N2 + N3;
       i += (size_t)gridDim.x * 256) {
    float x; unsigned short *ph, *pl; size_t o;
    if (i < N1)           { o = i;           x = gw[o];  ph = gwh;  pl = gwl; }
    else if (i < N1 + N2) { o = i - N1;      x = wih[o]; ph = wihh; pl = wihl; }
    else                  { o = i - N1 - N2; x = whh[o]; ph = whhh; pl = whhl; }
    unsigned short hi, lo;
    split_bf(x, hi, lo);
    ph[o] = hi; pl[o] = lo;
  }
}

__global__ void __launch_bounds__(256) k_wst(const float* __restrict__ Ws,
                                             float* __restrict__ wst) {
  size_t i = (size_t)blockIdx.x * 256 + threadIdx.x;
  if (i >= SZ_WST) return;
  int d = (int)(i >> 16);
  int j = (int)((i >> 8) & 255);
  int k = (int)(i & 255);
  wst[i] = Ws[((size_t)d * HH + k) * HH + j];
}

// ---------------- the persistent kernel ----------------
__global__ void __launch_bounds__(NTHR, 2) pe_main(
    const float* __restrict__ qin, const float* __restrict__ pin,
    const unsigned char* __restrict__ qmask,
    const float* __restrict__ vvec, const float* __restrict__ gateb,
    const float* __restrict__ bih, const float* __restrict__ bhh,
    float* __restrict__ out,
    float* __restrict__ fws, unsigned* __restrict__ upck,
    unsigned short* __restrict__ hws, unsigned* __restrict__ bar) {
  __shared__ __align__(16) unsigned short smem[55296];  // 110.6 KB
  unsigned short* sAh = smem;            // 9216 shorts
  unsigned short* sAl = smem + 9216;     // 9216 shorts
  unsigned short* warea = smem + 18432;  // 36864 shorts (resident weights / prologue B)
  float* fsm = (float*)smem;             // scratch for phases A & C2 (aliases sAh/sAl)

  float* qt   = fws + OFF_QT;
  float* pt   = fws + OFF_PT;
  float* gp   = fws + OFF_GP;
  float* gip  = fws + OFF_GIP;
  float* ghp  = fws + OFF_GHP;
  float* wst  = fws + OFF_WST;
  unsigned* upack = upck + UOFF_UPACK;
  unsigned* hpack = upck + UOFF_HPACK;
  unsigned short* wqth = hws + HOFF_WQTH;
  unsigned short* wqtl = hws + HOFF_WQTL;
  unsigned short* wpth = hws + HOFF_WPTH;
  unsigned short* wptl = hws + HOFF_WPTL;
  unsigned short* gwh  = hws + HOFF_GWH;
  unsigned short* wihh = hws + HOFF_WIHH;
  unsigned short* wihl = hws + HOFF_WIHL;
  unsigned short* whhh = hws + HOFF_WHHH;
  unsigned short* whhl = hws + HOFF_WHHL;

  const int blk = blockIdx.x;
  const int tid = threadIdx.x;
  const int lane = tid & 63;
  const int w = tid >> 6;
  unsigned gen = 0;

  // ---- prologue: q_temp / p_temp GEMMs ----
  for (int tt = blk; tt < 1840; tt += NBLK) {
    if (tt < 1600) {
      int d = tt / 800, rem = tt % 800, mt = rem >> 1, ntp = rem & 1;
      gemm_t<128, 0, true, true, false, 8>(sAh, sAl, warea,
          pin + (size_t)mt * BB * EE, EE, nullptr, 0, nullptr, nullptr,
          wpth + ((size_t)d * HH + ntp * 128) * EE,
          wptl + ((size_t)d * HH + ntp * 128) * EE, EE,
          pt + ((size_t)d * PL * BB + (size_t)mt * BB) * HH + ntp * 128, HH, 1, 0);
    } else {
      int u2 = tt - 1600;
      int d = u2 / 120, rem = u2 % 120, mt = rem >> 1, ntp = rem & 1;
      gemm_t<128, 0, true, true, false, 8>(sAh, sAl, warea,
          qin + (size_t)mt * BB * EE, EE, nullptr, 0, nullptr, nullptr,
          wqth + ((size_t)d * HH + ntp * 128) * EE,
          wqtl + ((size_t)d * HH + ntp * 128) * EE, EE,
          qt + ((size_t)d * QL * BB + (size_t)mt * BB) * HH + ntp * 128, HH, 1, 0);
    }
  }

  // ---- prologue: load this block's resident weight tile into LDS ----
  if (blk < 64) {               // gate: W single-bf16, NT=128, K=256
    const int d = blk >> 5, r5 = blk & 31, nt = r5 >> 2, ks = r5 & 3;
    const unsigned short* src = gwh + (size_t)(d * DD + nt * 128) * DD + ks * 256;
    for (int i = tid; i < 32768; i += NTHR) {
      int ch = i >> 13, n = (i >> 6) & 127, k = i & 63;
      warea[(ch * 128 + n) * LDK + k] = src[(size_t)n * DD + ch * 64 + k];
    }
  } else if (blk < 160) {       // gi: Wih hi/lo, NT=64, K=256
    const int g = blk - 64, d = g / 48, r = g % 48, nt = r >> 2, ks = r & 3;
    const unsigned short* sh = wihh + (size_t)(d * G3 + nt * 64) * DD + ks * 256;
    const unsigned short* sl = wihl + (size_t)(d * G3 + nt * 64) * DD + ks * 256;
    for (int i = tid; i < 16384; i += NTHR) {
      int ch = i >> 12, n = (i >> 6) & 63, k = i & 63;
      warea[(ch * 64 + n) * LDK + k]         = sh[(size_t)n * DD + ch * 64 + k];
      warea[18432 + (ch * 64 + n) * LDK + k] = sl[(size_t)n * DD + ch * 64 + k];
    }
  } else if (blk < 184) {       // gh: Whh hi/lo, NT=64, K=256
    const int g = blk - 160, d = g / 12, nt = g % 12;
    const unsigned short* sh = whhh + (size_t)(d * G3 + nt * 64) * HH;
    const unsigned short* sl = whhl + (size_t)(d * G3 + nt * 64) * HH;
    for (int i = tid; i < 16384; i += NTHR) {
      int ch = i >> 12, n = (i >> 6) & 63, k = i & 63;
      warea[(ch * 64 + n) * LDK + k]         = sh[(size_t)n * HH + ch * 64 + k];
      warea[18432 + (ch * 64 + n) * LDK + k] = sl[(size_t)n * HH + ch * 64 + k];
    }
  }

  // publish qt/pt (plain stores) once
  __builtin_amdgcn_fence(__ATOMIC_RELEASE, "agent");
  gbar(bar, ++gen);

  // per-(d,b) block-local state in LDS (live ranges don't overlap gemm staging)
  float* sm = fsm;            // 256
  float* sv = fsm + 256;      // 256
  float* slog = fsm + 512;    // 64
  float* swgt = fsm + 576;    // 64
  float* sstv = fsm + 640;    // 256 (state_temp; live C2 -> A only)
  float* spart = fsm + 896;   // 512
  float* hrow = fsm + 1408;   // 256
  if (tid < 256) sstv[tid] = 0.f;
  __syncthreads();

  const int d_ab = blk >> 7, b_ab = blk & 127;
  float hreg = 0.f;

  for (int s = 0; s < PL; ++s) {
    // ---------- phase A: attention + u-pack ----------
    {
      const int d = d_ab, b = b_ab;
      const int t = d ? (PL - 1 - s) : s;
      if (tid < 256) {
        sm[tid] = sstv[tid] + pt[(((size_t)d * PL + t) * BB + b) * HH + tid];
        sv[tid] = vvec[d * HH + tid];
      }
      __syncthreads();
      for (int q = w; q < QL; q += 8) {
        float a = 0.f;
#pragma unroll
        for (int jj = 0; jj < 4; jj++) {
          int j = lane + jj * 64;
          a += ftanh(qt[(((size_t)d * QL + q) * BB + b) * HH + j] + sm[j]) * sv[j];
        }
        for (int off = 32; off; off >>= 1) a += __shfl_down(a, off, 64);
        if (lane == 0) slog[q] = a;
      }
      __syncthreads();
      if (tid < 64) {
        float x = -3.0e38f;
        if (lane < QL) {
          x = slog[lane];
          if (qmask[lane * BB + b]) x = -3.0e38f;
        }
        float mx = x;
        for (int off = 32; off; off >>= 1) mx = fmaxf(mx, __shfl_xor(mx, off, 64));
        float e = (lane < QL) ? __expf(x - mx) : 0.f;
        float sum2 = e;
        for (int off = 32; off; off >>= 1) sum2 += __shfl_xor(sum2, off, 64);
        if (lane < QL) swgt[lane] = e * __builtin_amdgcn_rcpf(sum2);
      }
      __syncthreads();
      {
        // u-pack: pin part (col tid) + att part (col 512+tid)
        const size_t ub = ((size_t)d * BB + b) * DD;
        float pv = pin[((size_t)t * BB + b) * EE + tid];
        astu(&upack[ub + tid], packf(pv));
        float a0 = 0.f, a1 = 0.f, a2 = 0.f, a3 = 0.f;
        const float* qb = qin + (size_t)b * EE + tid;
        for (int q = 0; q < QL; q += 4) {
          a0 += swgt[q]     * qb[(size_t)q * BB * EE];
          a1 += swgt[q + 1] * qb[(size_t)(q + 1) * BB * EE];
          a2 += swgt[q + 2] * qb[(size_t)(q + 2) * BB * EE];
          a3 += swgt[q + 3] * qb[(size_t)(q + 3) * BB * EE];
        }
        astu(&upack[ub + EE + tid], packf((a0 + a1) + (a2 + a3)));
      }
    }
    gbar(bar, ++gen);

    // ---------- phase B: gate partials (0-63) + gh (160-183) ----------
    if (blk < 64) {
      const int d = blk >> 5, r5 = blk & 31, nt = r5 >> 2, ks = r5 & 3;
      gemm_t<128, 1, false, false, true, 4>(sAh, sAl, warea,
          nullptr, 0,
          upack + (size_t)d * BB * DD, DD,
          nullptr, nullptr, nullptr, nullptr, 0,
          gp + (size_t)d * BB * DD * 4 + (size_t)nt * 128 * 4 + ks, DD * 4, 4, ks * 256);
    } else if (blk >= 160 && blk < 184) {
      const int g = blk - 160, d = g / 12, nt = g % 12;
      gemm_t<64, 3, true, false, true, 4>(sAh, sAl, warea,
          nullptr, 0,
          hpack + (size_t)d * BB * HH, HH,
          nullptr, nullptr, nullptr, nullptr, 0,
          ghp + (size_t)d * BB * G3 + nt * 64, G3, 1, 0);
    }
    gbar(bar, ++gen);

    // ---------- phase C1: gi partials (64-159), x computed inline ----------
    if (blk >= 64 && blk < 160) {
      const int g = blk - 64, d = g / 48, r = g % 48, nt = r >> 2, ks = r & 3;
      gemm_t<64, 2, true, false, true, 4>(sAh, sAl, warea,
          nullptr, 0,
          upack + (size_t)d * BB * DD, DD,
          gp + (size_t)d * BB * DD * 4, gateb + (size_t)d * DD,
          nullptr, nullptr, 0,
          gip + (size_t)d * BB * G3 * 4 + (size_t)nt * 64 * 4 + ks, G3 * 4, 4, ks * 256);
    }
    gbar(bar, ++gen);

    // ---------- phase C2: GRU elementwise + output + state_temp GEMV ----------
    {
      const int d = d_ab, b = b_ab;
      const int j = tid & 255, half = tid >> 8;
      const int t = d ? (PL - 1 - s) : s;
      const size_t rb = (size_t)d * BB + b;
      float gi[3], gh[3];
#pragma unroll
      for (int c3 = 0; c3 < 3; c3++) {
        const unsigned long long* p =
            (const unsigned long long*)(gip + (rb * G3 + c3 * HH + j) * 4);
        unsigned long long x01 = aldull(p), x23 = aldull(p + 1);
        gi[c3] = bih[(size_t)d * G3 + c3 * HH + j] +
                 ((uf(x01) + ufh(x01)) + (uf(x23) + ufh(x23)));
        gh[c3] = ald(&ghp[rb * G3 + c3 * HH + j]) + bhh[(size_t)d * G3 + c3 * HH + j];
      }
      float r = sigm(gi[0] + gh[0]);
      float z = sigm(gi[1] + gh[1]);
      float n = ftanh(gi[2] + r * gh[2]);
      float hn = (1.f - z) * n + z * hreg;
      hreg = hn;
      if (half == 0) {
        out[((size_t)t * BB + b) * 512 + d * HH + j] = hn;
        astu(&hpack[rb * HH + j], packf(hn));
        hrow[j] = hn;
      }
      __syncthreads();
      float part = 0.f;
      const float* wr = wst + ((size_t)d * HH + j) * HH + (half << 7);
      const float* hr = hrow + (half << 7);
#pragma unroll
      for (int k = 0; k < 128; k += 4) {
        float4 w4 = *(const float4*)&wr[k];
        float4 h4 = *(const float4*)&hr[k];
        part += w4.x * h4.x + w4.y * h4.y + w4.z * h4.z + w4.w * h4.w;
      }
      spart[tid] = part;
      __syncthreads();
      if (tid < 256) sstv[tid] = spart[tid] + spart[tid + 256];
      __syncthreads();
    }
    // C2 -> A: no grid barrier (A consumes only block-local state + static tensors)
  }
}

// ---------------- launch ----------------
extern "C" void kernel_launch(void* const* d_in, const int* in_sizes, int n_in,
                              void* d_out, int out_size, void* d_ws, size_t ws_size,
                              hipStream_t stream) {
  const float* qin = (const float*)d_in[0];
  const float* pin = (const float*)d_in[1];
  const unsigned char* qmask = (const unsigned char*)d_in[2];
  const float* Wq  = (const float*)d_in[3];
  const float* Wp  = (const float*)d_in[4];
  const float* Ws  = (const float*)d_in[5];
  const float* v   = (const float*)d_in[6];
  const float* gw  = (const float*)d_in[7];
  const float* gb  = (const float*)d_in[8];
  const float* wih = (const float*)d_in[9];
  const float* whh = (const float*)d_in[10];
  const float* bih = (const float*)d_in[11];
  const float* bhh = (const float*)d_in[12];
  float* out = (float*)d_out;

  char* base = (char*)d_ws;
  float* fws = (float*)base;
  unsigned* upck = (unsigned*)(base + F32_TOT * sizeof(float));
  unsigned short* hws = (unsigned short*)(base + F32_TOT * sizeof(float) + U_TOT * sizeof(unsigned));
  unsigned* bar = (unsigned*)(base + F32_TOT * sizeof(float) + U_TOT * sizeof(unsigned) +
                              H_TOT * sizeof(unsigned short));
  size_t need = F32_TOT * sizeof(float) + U_TOT * sizeof(unsigned) +
                H_TOT * sizeof(unsigned short) + 8192;
  if (ws_size < need) return;

  // zero h-state + barrier slots (re-runs on every graph replay)
  hipMemsetAsync(upck + UOFF_HPACK, 0, (size_t)2 * BB * HH * sizeof(unsigned), stream);
  hipMemsetAsync(bar, 0, 4096, stream);

  k_transpose_qp<<<128, 256, 0, stream>>>(Wq, Wp,
      hws + HOFF_WQTH, hws + HOFF_WQTL, hws + HOFF_WPTH, hws + HOFF_WPTL);
  k_split_w<<<1024, 256, 0, stream>>>(gw, wih, whh,
      hws + HOFF_GWH, hws + HOFF_GWL, hws + HOFF_WIHH, hws + HOFF_WIHL,
      hws + HOFF_WHHH, hws + HOFF_WHHL);
  k_wst<<<(int)((SZ_WST + 255) / 256), 256, 0, stream>>>(Ws, fws + OFF_WST);
  pe_main<<<NBLK, NTHR, 0, stream>>>(qin, pin, qmask, v, gb, bih, bhh, out,
                                     fws, upck, hws, bar);
}